// Round 3
// baseline (707.576 us; speedup 1.0000x reference)
//
#include <hip/hip_runtime.h>

// Residual VQ, fully fused, exact-fp32 residual chain.
// Round 11: ng-split pair structure. LDS-read traffic is the bottleneck
// (16.8M ds_read_b128 = 327us of LDS pipe at T=1; T=2 halves it but halves
// occupancy since tiles*waves=4096 is fixed). Fix: split the CODEBOOK
// across wave pairs: 256-thr blocks, 4 waves = 2 point-groups x 2 halves.
// Each wave: 2 M-tiles (32 pts) x half of each 32-cw chunk -> 8.4M reads
// (164us floor) at 4096 waves. Persistent R dropped (-64 VGPR): R is
// recomputed per stage as x - c_w0 - c_w1 - ... in ascending order ->
// bitwise-identical to the incremental chain. Per-tile MFMA chain order
// (hi*bh, lo*bh, hi*bl; kk ascending) UNCHANGED - approx-distance bits are
// part of the passing contract. Cross-wave top-2 merge is (d, then lower
// index) lexicographic, provably bit-identical to the old single-stream
// upd2 result; m-column shfl merge unchanged.
// N=65536 pts, D=128, S=4 stages, K=2048 codewords.
// Out (flat f32): x_q [N*D] @0, mean_loss @N*D, indices [N,S] as float @N*D+1.

#define N_PTS   65536
#define DDIM    128
#define NSTAGE  4
#define KCB     2048
#define BETA_F  0.25f

#define XQ_SIZE (N_PTS * DDIM)
#define IDX_OFF (XQ_SIZE + 1)

// ws layout (float units)
#define WS_LOSS 0                         // 4 floats
#define WS_CN   16                        // NSTAGE*KCB floats
#define WS_FRAG (16 + NSTAGE * KCB)       // frag stream, 16B-aligned
#define FRAG_S8 (32 * 32 * 64)            // short8 per stage = 65536 (1 MB)

typedef __attribute__((ext_vector_type(8))) short short8;
typedef __attribute__((ext_vector_type(4))) float f32x4;

__device__ inline short f2bf(float x) {            // RTNE bf16
    union { float f; unsigned u; } v; v.f = x;
    unsigned r = v.u + 0x7FFFu + ((v.u >> 16) & 1u);
    return (short)(r >> 16);
}
__device__ inline float bf2f(short h) {
    union { unsigned u; float f; } v; v.u = ((unsigned)(unsigned short)h) << 16;
    return v.f;
}
__device__ inline void gload_lds16(const void* g, void* l) {
    __builtin_amdgcn_global_load_lds(
        (const __attribute__((address_space(1))) unsigned int*)g,
        (__attribute__((address_space(3))) unsigned int*)l, 16, 0, 0);
}
__device__ inline void upd2(float& d1, int& i1, float& d2, int& i2, float d, int i) {
    bool lt1 = d < d1;
    bool lt2 = d < d2;
    float nd2 = lt1 ? d1 : (lt2 ? d : d2);
    int   ni2 = lt1 ? i1 : (lt2 ? i : i2);
    d1 = lt1 ? d : d1;  i1 = lt1 ? i : i1;
    d2 = nd2;           i2 = ni2;
}
// lexicographic (d, then lower index) insert - used ONLY for the cross-wave
// merge, where it provably reproduces the single-ascending-stream result.
__device__ inline void upd2i(float& d1, int& i1, float& d2, int& i2, float d, int i) {
    bool w1 = (d < d1) || (d == d1 && i < i1);
    bool w2 = (d < d2) || (d == d2 && i < i2);
    float nd2 = w1 ? d1 : (w2 ? d : d2);
    int   ni2 = w1 ? i1 : (w2 ? i : i2);
    d1 = w1 ? d : d1;  i1 = w1 ? i : i1;
    d2 = nd2;          i2 = ni2;
}

// ||c||^2 per codeword + zero loss accumulators
__global__ void cnorm_init(const float* __restrict__ cb, float* __restrict__ ws) {
    int t = blockIdx.x * blockDim.x + threadIdx.x;   // 131072 threads
    int row = t >> 4;                                // 0..8191 (s*K + k)
    int q   = t & 15;
    const float4* rp = (const float4*)(cb + (size_t)row * DDIM);
    float s = 0.f;
    #pragma unroll
    for (int j = 0; j < 2; ++j) {
        float4 v = rp[q * 2 + j];
        s += v.x * v.x + v.y * v.y + v.z * v.z + v.w * v.w;
    }
    #pragma unroll
    for (int m = 1; m < 16; m <<= 1) s += __shfl_xor(s, m);
    if (q == 0) ws[WS_CN + row] = s;
    if (t < 4) ws[WS_LOSS + t] = 0.f;
}

// Pack codebook into MFMA-B-frag-linear bf16 hi/lo layout (UNCHANGED):
// id = (((s*32 + C64)*4 + nt)*4 + kk)*2*64 + h*64 + lane ; 16 B per id.
// lane's 8 bf16 = cb[s][C64*64 + nt*16 + (lane&15)][kk*32 + (lane>>4)*8 .. +8]
// New consumption view: 32-cw chunk c (0..63) = short8[c*1024 .. c*1024+1023].
__global__ void frag_pack(const float* __restrict__ cb, float* __restrict__ ws) {
    int id   = blockIdx.x * 256 + threadIdx.x;       // 0..262143
    int lane = id & 63;
    int h    = (id >> 6) & 1;
    int kk   = (id >> 7) & 3;
    int nt   = (id >> 9) & 3;
    int c    = (id >> 11) & 31;
    int s    = (id >> 16);
    int row  = c * 64 + nt * 16 + (lane & 15);
    int koff = kk * 32 + (lane >> 4) * 8;
    const float* src = cb + ((size_t)(s * KCB + row) * DDIM + koff);
    short8 v;
    #pragma unroll
    for (int j = 0; j < 8; ++j) {
        float xv = src[j];
        short hi = f2bf(xv);
        if (h) { v[j] = f2bf(xv - bf2f(hi)); }
        else   { v[j] = hi; }
    }
    ((short8*)(ws + WS_FRAG))[id] = v;
}

#define MFMA16(A, B, C) __builtin_amdgcn_mfma_f32_16x16x32_bf16(A, B, C, 0, 0, 0)

__global__ __launch_bounds__(256, 3)
void rvq_fused(const float* __restrict__ x, const float* __restrict__ cb,
               float* __restrict__ ws, float* __restrict__ out) {
    __shared__ short8 Bbuf[2][1024];                 // 2 x 16 KB (32-cw chunks)
    __shared__ float  sCn[KCB];                      // 8 KB -> total 40960 B

    const int t    = threadIdx.x;
    const int lane = t & 63;
    const int w    = t >> 6;                         // wave 0..3
    const int grp  = w >> 1;                         // point group 0,1
    const int h    = w & 1;                          // codebook half (nt parity)
    const int m    = lane & 15;
    const int q    = lane >> 4;
    const int bofs = h * 512 + lane;                 // B-frag base within chunk
    const size_t pbase = (size_t)blockIdx.x * 64 + grp * 32;
    const size_t pt[2] = {pbase + m, pbase + 16 + m};

    const short8* fragAll = (const short8*)(ws + WS_FRAG);

    // Split-bf16 A-frags (stage 0: split of x). No persistent fp32 R.
    short8 Ahi[2][4], Alo[2][4];
    #pragma unroll
    for (int tile = 0; tile < 2; ++tile)
        #pragma unroll
        for (int kk = 0; kk < 4; ++kk) {
            const float* rp = x + pt[tile] * DDIM + kk * 32 + q * 8;
            float4 v0 = *(const float4*)rp;
            float4 v1 = *(const float4*)(rp + 4);
            float xv[8] = {v0.x, v0.y, v0.z, v0.w, v1.x, v1.y, v1.z, v1.w};
            short8 hi8, lo8;
            #pragma unroll
            for (int j = 0; j < 8; ++j) {
                short hi = f2bf(xv[j]);
                hi8[j] = hi;
                lo8[j] = f2bf(xv[j] - bf2f(hi));
            }
            Ahi[tile][kk] = hi8; Alo[tile][kk] = lo8;
        }

    int winA[2] = {0, 0}, winB[2] = {0, 0}, winC[2] = {0, 0};
    float lossAcc = 0.f;

    // prefetch stage 0 chunk 0 + stage 0 cn
    #pragma unroll
    for (int j = 0; j < 4; ++j) {
        int idx = t + j * 256;
        gload_lds16(fragAll + idx, &Bbuf[0][idx]);
    }
    #pragma unroll
    for (int j = 0; j < 2; ++j) {
        int idx = t + j * 256;
        gload_lds16(ws + WS_CN + 4 * idx, &sCn[4 * idx]);
    }

    #pragma unroll 1
    for (int s = 0; s < NSTAGE; ++s) {
        const short8* frag = fragAll + (size_t)s * FRAG_S8;
        const float*  cbs  = cb + (size_t)s * KCB * DDIM;

        float d1[2][4], d2[2][4]; int i1[2][4], i2[2][4];
        #pragma unroll
        for (int tile = 0; tile < 2; ++tile)
            #pragma unroll
            for (int r = 0; r < 4; ++r) {
                d1[tile][r] = 3e38f; d2[tile][r] = 3e38f;
                i1[tile][r] = 0;     i2[tile][r] = 1;
            }

        // Deferred-fold ping-pong: X filled at even chunks, Y at odd.
        // Fake pends evicted by first real candidates (d = +6e37).
        const f32x4 fake = {-3e37f, -3e37f, -3e37f, -3e37f};
        f32x4 Xa0 = fake, Xa1 = fake, Ya0 = fake, Ya1 = fake;
        int cwX = 0, cwY = 0;

        #pragma unroll 1
        for (int c2 = 0; c2 < 32; ++c2) {
            const int ce = c2 * 2;
            // ---- chunk ce (even, Bbuf[0]) ----
            __syncthreads();
            {   // prefetch chunk ce+1 -> Bbuf[1]
                const short8* src = frag + (size_t)(ce + 1) * 1024;
                #pragma unroll
                for (int j = 0; j < 4; ++j) {
                    int idx = t + j * 256;
                    gload_lds16(src + idx, &Bbuf[1][idx]);
                }
            }
            {   // fold Y (chunk ce-1; fakes at c2==0)
                float cnv = sCn[cwY];
                #pragma unroll
                for (int r = 0; r < 4; ++r) {
                    float dt0 = fmaf(-2.f, Ya0[r], cnv);
                    upd2(d1[0][r], i1[0][r], d2[0][r], i2[0][r], dt0, cwY);
                    float dt1 = fmaf(-2.f, Ya1[r], cnv);
                    upd2(d1[1][r], i1[1][r], d2[1][r], i2[1][r], dt1, cwY);
                }
            }
            {   // chain (this wave's half of chunk ce) -> X
                const short8* B = Bbuf[0];
                f32x4 ca0 = {0.f, 0.f, 0.f, 0.f};
                f32x4 ca1 = {0.f, 0.f, 0.f, 0.f};
                #pragma unroll
                for (int kk = 0; kk < 4; ++kk) {
                    short8 bh = B[bofs + kk * 128];
                    short8 bl = B[bofs + kk * 128 + 64];
                    ca0 = MFMA16(Ahi[0][kk], bh, ca0);
                    ca1 = MFMA16(Ahi[1][kk], bh, ca1);
                    ca0 = MFMA16(Alo[0][kk], bh, ca0);
                    ca1 = MFMA16(Alo[1][kk], bh, ca1);
                    ca0 = MFMA16(Ahi[0][kk], bl, ca0);
                    ca1 = MFMA16(Ahi[1][kk], bl, ca1);
                }
                Xa0 = ca0; Xa1 = ca1;
                cwX = ce * 32 + h * 16 + m;
            }
            // ---- chunk ce+1 (odd, Bbuf[1]) ----
            __syncthreads();
            if (c2 + 1 < 32) {                       // prefetch ce+2 -> Bbuf[0]
                const short8* src = frag + (size_t)(ce + 2) * 1024;
                #pragma unroll
                for (int j = 0; j < 4; ++j) {
                    int idx = t + j * 256;
                    gload_lds16(src + idx, &Bbuf[0][idx]);
                }
            } else if (s + 1 < NSTAGE) {             // next-stage chunk 0
                const short8* src = fragAll + (size_t)(s + 1) * FRAG_S8;
                #pragma unroll
                for (int j = 0; j < 4; ++j) {
                    int idx = t + j * 256;
                    gload_lds16(src + idx, &Bbuf[0][idx]);
                }
            }
            {   // fold X (chunk ce)
                float cnv = sCn[cwX];
                #pragma unroll
                for (int r = 0; r < 4; ++r) {
                    float dt0 = fmaf(-2.f, Xa0[r], cnv);
                    upd2(d1[0][r], i1[0][r], d2[0][r], i2[0][r], dt0, cwX);
                    float dt1 = fmaf(-2.f, Xa1[r], cnv);
                    upd2(d1[1][r], i1[1][r], d2[1][r], i2[1][r], dt1, cwX);
                }
            }
            {   // chain (half of chunk ce+1) -> Y
                const short8* B = Bbuf[1];
                f32x4 ca0 = {0.f, 0.f, 0.f, 0.f};
                f32x4 ca1 = {0.f, 0.f, 0.f, 0.f};
                #pragma unroll
                for (int kk = 0; kk < 4; ++kk) {
                    short8 bh = B[bofs + kk * 128];
                    short8 bl = B[bofs + kk * 128 + 64];
                    ca0 = MFMA16(Ahi[0][kk], bh, ca0);
                    ca1 = MFMA16(Ahi[1][kk], bh, ca1);
                    ca0 = MFMA16(Alo[0][kk], bh, ca0);
                    ca1 = MFMA16(Alo[1][kk], bh, ca1);
                    ca0 = MFMA16(Ahi[0][kk], bl, ca0);
                    ca1 = MFMA16(Ahi[1][kk], bl, ca1);
                }
                Ya0 = ca0; Ya1 = ca1;
                cwY = (ce + 1) * 32 + h * 16 + m;
            }
        }
        // final fold Y (chunk 63)
        {
            float cnv = sCn[cwY];
            #pragma unroll
            for (int r = 0; r < 4; ++r) {
                float dt0 = fmaf(-2.f, Ya0[r], cnv);
                upd2(d1[0][r], i1[0][r], d2[0][r], i2[0][r], dt0, cwY);
                float dt1 = fmaf(-2.f, Ya1[r], cnv);
                upd2(d1[1][r], i1[1][r], d2[1][r], i2[1][r], dt1, cwY);
            }
        }

        // ---- cross-wave (half0/half1) lexicographic top-2 merge, 2 rounds
        // through the dead Bbuf[1] (16 KB). Bbuf[0] holds next-stage chunk 0
        // (in flight) and is untouched.
        {
            float* exch = (float*)&Bbuf[1][0];
            #pragma unroll
            for (int tile = 0; tile < 2; ++tile) {
                __syncthreads();     // round entry: region free
                float4* wp = (float4*)(exch + w * 1024) + lane * 4;
                wp[0] = make_float4(d1[tile][0], d1[tile][1], d1[tile][2], d1[tile][3]);
                wp[1] = make_float4(d2[tile][0], d2[tile][1], d2[tile][2], d2[tile][3]);
                wp[2] = make_float4(__int_as_float(i1[tile][0]), __int_as_float(i1[tile][1]),
                                    __int_as_float(i1[tile][2]), __int_as_float(i1[tile][3]));
                wp[3] = make_float4(__int_as_float(i2[tile][0]), __int_as_float(i2[tile][1]),
                                    __int_as_float(i2[tile][2]), __int_as_float(i2[tile][3]));
                __syncthreads();
                const float4* rp = (const float4*)(exch + (w ^ 1) * 1024) + lane * 4;
                float4 pd1 = rp[0], pd2 = rp[1], pi1 = rp[2], pi2 = rp[3];
                upd2i(d1[tile][0], i1[tile][0], d2[tile][0], i2[tile][0], pd1.x, __float_as_int(pi1.x));
                upd2i(d1[tile][1], i1[tile][1], d2[tile][1], i2[tile][1], pd1.y, __float_as_int(pi1.y));
                upd2i(d1[tile][2], i1[tile][2], d2[tile][2], i2[tile][2], pd1.z, __float_as_int(pi1.z));
                upd2i(d1[tile][3], i1[tile][3], d2[tile][3], i2[tile][3], pd1.w, __float_as_int(pi1.w));
                upd2i(d1[tile][0], i1[tile][0], d2[tile][0], i2[tile][0], pd2.x, __float_as_int(pi2.x));
                upd2i(d1[tile][1], i1[tile][1], d2[tile][1], i2[tile][1], pd2.y, __float_as_int(pi2.y));
                upd2i(d1[tile][2], i1[tile][2], d2[tile][2], i2[tile][2], pd2.z, __float_as_int(pi2.z));
                upd2i(d1[tile][3], i1[tile][3], d2[tile][3], i2[tile][3], pd2.w, __float_as_int(pi2.w));
            }
        }

        // m-column merge (unchanged semantics)
        #pragma unroll
        for (int mm = 1; mm < 16; mm <<= 1) {
            #pragma unroll
            for (int tile = 0; tile < 2; ++tile)
                #pragma unroll
                for (int r = 0; r < 4; ++r) {
                    float od1 = __shfl_xor(d1[tile][r], mm); int oi1 = __shfl_xor(i1[tile][r], mm);
                    float od2 = __shfl_xor(d2[tile][r], mm); int oi2 = __shfl_xor(i2[tile][r], mm);
                    upd2(d1[tile][r], i1[tile][r], d2[tile][r], i2[tile][r], od1, oi1);
                    upd2(d1[tile][r], i1[tile][r], d2[tile][r], i2[tile][r], od2, oi2);
                }
        }

        // recheck + update (both waves of a pair run identically so both
        // hold next-stage A-frags; writes gated to h==0)
        if (s + 1 < NSTAGE || h == 0) {
            #pragma unroll
            for (int tile = 0; tile < 2; ++tile) {
                // transpose: point m's merged top-2 lives at lanes q=(m>>2)
                int srcLane = (m >> 2) * 16;
                int ga0 = __shfl(i1[tile][0], srcLane), gb0 = __shfl(i2[tile][0], srcLane);
                int ga1 = __shfl(i1[tile][1], srcLane), gb1 = __shfl(i2[tile][1], srcLane);
                int ga2 = __shfl(i1[tile][2], srcLane), gb2 = __shfl(i2[tile][2], srcLane);
                int ga3 = __shfl(i1[tile][3], srcLane), gb3 = __shfl(i2[tile][3], srcLane);
                int rs = m & 3;
                int ia = rs == 0 ? ga0 : rs == 1 ? ga1 : rs == 2 ? ga2 : ga3;
                int ib = rs == 0 ? gb0 : rs == 1 ? gb1 : rs == 2 ? gb2 : gb3;

                // recompute exact R_s = x - c_w0 - ... - c_w(s-1), ascending:
                // bitwise-identical to the incremental chain.
                float Rt[4][8];
                #pragma unroll
                for (int kk = 0; kk < 4; ++kk) {
                    const float* rp = x + pt[tile] * DDIM + kk * 32 + q * 8;
                    float4 v0 = *(const float4*)rp, v1 = *(const float4*)(rp + 4);
                    Rt[kk][0] = v0.x; Rt[kk][1] = v0.y; Rt[kk][2] = v0.z; Rt[kk][3] = v0.w;
                    Rt[kk][4] = v1.x; Rt[kk][5] = v1.y; Rt[kk][6] = v1.z; Rt[kk][7] = v1.w;
                }
                if (s > 0) {
                    const float* cr = cb + ((size_t)(0 * KCB) + winA[tile]) * DDIM;
                    #pragma unroll
                    for (int kk = 0; kk < 4; ++kk) {
                        const float* p = cr + kk * 32 + q * 8;
                        float4 c0 = *(const float4*)p, c1 = *(const float4*)(p + 4);
                        float cv[8] = {c0.x, c0.y, c0.z, c0.w, c1.x, c1.y, c1.z, c1.w};
                        #pragma unroll
                        for (int j = 0; j < 8; ++j) Rt[kk][j] -= cv[j];
                    }
                }
                if (s > 1) {
                    const float* cr = cb + ((size_t)(1 * KCB) + winB[tile]) * DDIM;
                    #pragma unroll
                    for (int kk = 0; kk < 4; ++kk) {
                        const float* p = cr + kk * 32 + q * 8;
                        float4 c0 = *(const float4*)p, c1 = *(const float4*)(p + 4);
                        float cv[8] = {c0.x, c0.y, c0.z, c0.w, c1.x, c1.y, c1.z, c1.w};
                        #pragma unroll
                        for (int j = 0; j < 8; ++j) Rt[kk][j] -= cv[j];
                    }
                }
                if (s > 2) {
                    const float* cr = cb + ((size_t)(2 * KCB) + winC[tile]) * DDIM;
                    #pragma unroll
                    for (int kk = 0; kk < 4; ++kk) {
                        const float* p = cr + kk * 32 + q * 8;
                        float4 c0 = *(const float4*)p, c1 = *(const float4*)(p + 4);
                        float cv[8] = {c0.x, c0.y, c0.z, c0.w, c1.x, c1.y, c1.z, c1.w};
                        #pragma unroll
                        for (int j = 0; j < 8; ++j) Rt[kk][j] -= cv[j];
                    }
                }

                // exact fp32 recheck of top-2
                float pa = 0.f, pb = 0.f, pr = 0.f;
                #pragma unroll
                for (int kk = 0; kk < 4; ++kk) {
                    const float* pav = cbs + (size_t)ia * DDIM + kk * 32 + q * 8;
                    const float* pbv = cbs + (size_t)ib * DDIM + kk * 32 + q * 8;
                    float4 a0 = *(const float4*)pav, a1 = *(const float4*)(pav + 4);
                    float4 b0 = *(const float4*)pbv, b1 = *(const float4*)(pbv + 4);
                    float av[8] = {a0.x, a0.y, a0.z, a0.w, a1.x, a1.y, a1.z, a1.w};
                    float bv[8] = {b0.x, b0.y, b0.z, b0.w, b1.x, b1.y, b1.z, b1.w};
                    #pragma unroll
                    for (int j = 0; j < 8; ++j) {
                        float rv = Rt[kk][j];
                        pa += rv * av[j];
                        pb += rv * bv[j];
                        pr += rv * rv;
                    }
                }
                pa += __shfl_xor(pa, 16); pa += __shfl_xor(pa, 32);
                pb += __shfl_xor(pb, 16); pb += __shfl_xor(pb, 32);
                pr += __shfl_xor(pr, 16); pr += __shfl_xor(pr, 32);
                float dA = sCn[ia] - 2.f * pa;
                float dB = sCn[ib] - 2.f * pb;
                bool bw = (dB < dA) || (dB == dA && ib < ia);  // first-occurrence
                int  wi = bw ? ib : ia;
                if (q == 0 && h == 0) {
                    out[IDX_OFF + pt[tile] * NSTAGE + s] = (float)wi;
                    lossAcc += (bw ? dB : dA) + pr;            // ||c - r||^2
                }
                if (s == 0) winA[tile] = wi;
                else if (s == 1) winB[tile] = wi;
                else if (s == 2) winC[tile] = wi;

                // update: Rt -= c_win; re-split frags; last stage: x_q = x - R
                const float* cwr = cbs + (size_t)wi * DDIM;
                #pragma unroll
                for (int kk = 0; kk < 4; ++kk) {
                    const float* pwv = cwr + kk * 32 + q * 8;
                    float4 w0 = *(const float4*)pwv, w1 = *(const float4*)(pwv + 4);
                    float wv[8] = {w0.x, w0.y, w0.z, w0.w, w1.x, w1.y, w1.z, w1.w};
                    short8 hi8, lo8;
                    #pragma unroll
                    for (int j = 0; j < 8; ++j) {
                        float v = Rt[kk][j] - wv[j];
                        Rt[kk][j] = v;
                        short hi = f2bf(v);
                        hi8[j] = hi;
                        lo8[j] = f2bf(v - bf2f(hi));
                    }
                    Ahi[tile][kk] = hi8; Alo[tile][kk] = lo8;
                    if (s == NSTAGE - 1) {           // h==0 only reaches here
                        const float* xp = x + pt[tile] * DDIM + kk * 32 + q * 8;
                        float4 x0 = *(const float4*)xp, x1 = *(const float4*)(xp + 4);
                        float* op = out + pt[tile] * DDIM + kk * 32 + q * 8;
                        *(float4*)op = make_float4(x0.x - Rt[kk][0], x0.y - Rt[kk][1],
                                                   x0.z - Rt[kk][2], x0.w - Rt[kk][3]);
                        *(float4*)(op + 4) = make_float4(x1.x - Rt[kk][4], x1.y - Rt[kk][5],
                                                         x1.z - Rt[kk][6], x1.w - Rt[kk][7]);
                    }
                }
            }
        }

        // stage-end barrier: sCn reads done before next-stage overwrite
        __syncthreads();
        if (s + 1 < NSTAGE) {
            const float* cnn = ws + WS_CN + (s + 1) * KCB;
            #pragma unroll
            for (int j = 0; j < 2; ++j) {
                int idx = t + j * 256;
                gload_lds16(cnn + 4 * idx, &sCn[4 * idx]);
            }
        }
    }

    // loss: wave reduce, one atomic per wave (h==1 waves contribute 0)
    #pragma unroll
    for (int mm = 1; mm < 64; mm <<= 1)
        lossAcc += __shfl_xor(lossAcc, mm);
    if (lane == 0)
        atomicAdd(ws + WS_LOSS, lossAcc);
}

__global__ void rvq_finalize(const float* __restrict__ ws, float* __restrict__ out) {
    float sum = ws[0] + ws[1] + ws[2] + ws[3];
    out[XQ_SIZE] = (1.f + BETA_F) * sum /
                   ((float)NSTAGE * (float)N_PTS * (float)DDIM);
}

extern "C" void kernel_launch(void* const* d_in, const int* in_sizes, int n_in,
                              void* d_out, int out_size, void* d_ws, size_t ws_size,
                              hipStream_t stream) {
    const float* x  = (const float*)d_in[0];
    const float* cb = (const float*)d_in[1];
    float* out = (float*)d_out;
    float* ws  = (float*)d_ws;

    cnorm_init<<<512, 256, 0, stream>>>(cb, ws);
    frag_pack<<<1024, 256, 0, stream>>>(cb, ws);
    rvq_fused<<<1024, 256, 0, stream>>>(x, cb, ws, out);
    rvq_finalize<<<1, 1, 0, stream>>>(ws, out);
}

// Round 4
// 546.808 us; speedup vs baseline: 1.2940x; 1.2940x over previous
//
#include <hip/hip_runtime.h>

// Residual VQ, fully fused, exact-fp32 residual chain.
// Round 12: R9 structure (512 thr, 8 waves x 16 pts, 32KB chunks) + three
// bitwise-safe scheduling fixes for the per-wave ds_read->MFMA serialization
// (R9: every pipe <=35% busy, wall ~4x pipe demand, VGPR squeezed to 64):
//  (1) hand-pipelined B-frag prefetch (kk0/1 of ng+1 loaded during ng's
//      chain; kk2/3 + next-ng reads issued mid-chain) - reads move EARLIER
//      only, same values, same MFMA order -> bit-identical.
//  (2) counted-vmcnt dual-barrier per chunk (issue c+1; vmcnt(4); s_barrier;
//      compute; s_barrier) - no vmcnt(0) drains in the chunk loop.
//  (3) stage-tail syncs use lgkmcnt(0)-only barriers so the cross-stage
//      chunk-0 DMA stays in flight.
// Per-tile MFMA chain order (hi*bh, lo*bh, hi*bl; kk ascending) UNCHANGED -
// approx-distance bits are part of the passing contract. Fold stream
// (ascending cw, 1-ng deferred X/Y ping-pong) unchanged.
// N=65536 pts, D=128, S=4 stages, K=2048 codewords.
// Out (flat f32): x_q [N*D] @0, mean_loss @N*D, indices [N,S] as float @N*D+1.

#define N_PTS   65536
#define DDIM    128
#define NSTAGE  4
#define KCB     2048
#define BETA_F  0.25f

#define XQ_SIZE (N_PTS * DDIM)
#define IDX_OFF (XQ_SIZE + 1)

// ws layout (float units)
#define WS_LOSS 0                         // 4 floats
#define WS_CN   16                        // NSTAGE*KCB floats
#define WS_FRAG (16 + NSTAGE * KCB)       // frag stream, 16B-aligned
#define FRAG_S8 (32 * 32 * 64)            // short8 per stage = 65536 (1 MB)

typedef __attribute__((ext_vector_type(8))) short short8;
typedef __attribute__((ext_vector_type(4))) float f32x4;

// counted-vmcnt barrier: my chunk-c loads landed (4 newest = c+1's in flight)
#define BAR_VM4()  asm volatile("s_waitcnt vmcnt(4)\n\ts_barrier" ::: "memory")
#define BAR_VM0()  asm volatile("s_waitcnt vmcnt(0)\n\ts_barrier" ::: "memory")
#define BAR_ONLY() asm volatile("s_barrier" ::: "memory")
#define BAR_LGKM() asm volatile("s_waitcnt lgkmcnt(0)\n\ts_barrier" ::: "memory")

__device__ inline short f2bf(float x) {            // RTNE bf16
    union { float f; unsigned u; } v; v.f = x;
    unsigned r = v.u + 0x7FFFu + ((v.u >> 16) & 1u);
    return (short)(r >> 16);
}
__device__ inline float bf2f(short h) {
    union { unsigned u; float f; } v; v.u = ((unsigned)(unsigned short)h) << 16;
    return v.f;
}
__device__ inline void gload_lds16(const void* g, void* l) {
    __builtin_amdgcn_global_load_lds(
        (const __attribute__((address_space(1))) unsigned int*)g,
        (__attribute__((address_space(3))) unsigned int*)l, 16, 0, 0);
}
__device__ inline void upd2(float& d1, int& i1, float& d2, int& i2, float d, int i) {
    bool lt1 = d < d1;
    bool lt2 = d < d2;
    float nd2 = lt1 ? d1 : (lt2 ? d : d2);
    int   ni2 = lt1 ? i1 : (lt2 ? i : i2);
    d1 = lt1 ? d : d1;  i1 = lt1 ? i : i1;
    d2 = nd2;           i2 = ni2;
}

// ||c||^2 per codeword + zero loss accumulators
__global__ void cnorm_init(const float* __restrict__ cb, float* __restrict__ ws) {
    int t = blockIdx.x * blockDim.x + threadIdx.x;   // 131072 threads
    int row = t >> 4;                                // 0..8191 (s*K + k)
    int q   = t & 15;
    const float4* rp = (const float4*)(cb + (size_t)row * DDIM);
    float s = 0.f;
    #pragma unroll
    for (int j = 0; j < 2; ++j) {
        float4 v = rp[q * 2 + j];
        s += v.x * v.x + v.y * v.y + v.z * v.z + v.w * v.w;
    }
    #pragma unroll
    for (int m = 1; m < 16; m <<= 1) s += __shfl_xor(s, m);
    if (q == 0) ws[WS_CN + row] = s;
    if (t < 4) ws[WS_LOSS + t] = 0.f;
}

// Pack codebook into MFMA-B-frag-linear bf16 hi/lo layout:
// id = (((s*32 + c)*4 + nt)*4 + kk)*2*64 + h*64 + lane ; 16 B per id.
// lane's 8 bf16 = cb[s][c*64 + nt*16 + (lane&15)][kk*32 + (lane>>4)*8 .. +8]
__global__ void frag_pack(const float* __restrict__ cb, float* __restrict__ ws) {
    int id   = blockIdx.x * 256 + threadIdx.x;       // 0..262143
    int lane = id & 63;
    int h    = (id >> 6) & 1;
    int kk   = (id >> 7) & 3;
    int nt   = (id >> 9) & 3;
    int c    = (id >> 11) & 31;
    int s    = (id >> 16);
    int row  = c * 64 + nt * 16 + (lane & 15);
    int koff = kk * 32 + (lane >> 4) * 8;
    const float* src = cb + ((size_t)(s * KCB + row) * DDIM + koff);
    short8 v;
    #pragma unroll
    for (int j = 0; j < 8; ++j) {
        float xv = src[j];
        short hi = f2bf(xv);
        if (h) { v[j] = f2bf(xv - bf2f(hi)); }
        else   { v[j] = hi; }
    }
    ((short8*)(ws + WS_FRAG))[id] = v;
}

#define MFMA16(A, B, C) __builtin_amdgcn_mfma_f32_16x16x32_bf16(A, B, C, 0, 0, 0)

__global__ __launch_bounds__(512, 4)
void rvq_fused(const float* __restrict__ x, const float* __restrict__ cb,
               float* __restrict__ ws, float* __restrict__ out) {
    __shared__ short8 Bbuf[2][2048];                 // 2 x 32 KB
    __shared__ float  sCn[KCB];                      // 8 KB, per-stage ||c||^2
    __shared__ int    sC1[128], sC2[128];

    const int t    = threadIdx.x;
    const int lane = t & 63;
    const int w    = t >> 6;                         // wave 0..7
    const int m    = lane & 15;
    const int q    = lane >> 4;
    const size_t pt = (size_t)blockIdx.x * 128 + w * 16 + m;  // wave's 16 pts

    const short8* fragAll = (const short8*)(ws + WS_FRAG);

    // Exact fp32 residual R + split-bf16 A-frags, one M-tile per wave.
    float  R[4][8];
    short8 Ahi[4], Alo[4];
    #pragma unroll
    for (int kk = 0; kk < 4; ++kk) {
        const float* rp = x + pt * DDIM + kk * 32 + q * 8;
        float4 v0 = *(const float4*)rp;
        float4 v1 = *(const float4*)(rp + 4);
        R[kk][0] = v0.x; R[kk][1] = v0.y;
        R[kk][2] = v0.z; R[kk][3] = v0.w;
        R[kk][4] = v1.x; R[kk][5] = v1.y;
        R[kk][6] = v1.z; R[kk][7] = v1.w;
        short8 hi8, lo8;
        #pragma unroll
        for (int j = 0; j < 8; ++j) {
            short hi = f2bf(R[kk][j]);
            hi8[j] = hi;
            lo8[j] = f2bf(R[kk][j] - bf2f(hi));
        }
        Ahi[kk] = hi8; Alo[kk] = lo8;
    }

    float lossAcc = 0.f;

    // prefetch stage 0 chunk 0 + stage 0 cn
    #pragma unroll
    for (int j = 0; j < 4; ++j) {
        int idx = t + j * 512;
        gload_lds16(fragAll + idx, &Bbuf[0][idx]);
    }
    gload_lds16(ws + WS_CN + 4 * t, &sCn[4 * t]);    // 512 x 16B = 8 KB

    #pragma unroll 1
    for (int s = 0; s < NSTAGE; ++s) {
        const short8* frag = fragAll + (size_t)s * FRAG_S8;
        const float*  cbs  = cb + (size_t)s * KCB * DDIM;

        float d1[4], d2[4]; int i1[4], i2[4];
        #pragma unroll
        for (int r = 0; r < 4; ++r) {
            d1[r] = 3e38f; d2[r] = 3e38f;
            i1[r] = 0;     i2[r] = 1;
        }

        // Deferred-fold pending acc sets, ping-pong X/Y. Y starts fake
        // (dist=+6e37, evicted by the first two real candidates); cwp=0.
        const f32x4 fake = {-3e37f, -3e37f, -3e37f, -3e37f};
        f32x4 Xa = fake, Ya = fake;
        int cwp = 0;

        #pragma unroll 1
        for (int c = 0; c < 32; ++c) {
            // issue next-chunk DMA BEFORE the barrier (counted vmcnt keeps it
            // in flight); buf[(c+1)&1] was released by last iter's barrier.
            if (c + 1 < 32) {
                const short8* src = frag + (size_t)(c + 1) * 2048;
                #pragma unroll
                for (int j = 0; j < 4; ++j) {
                    int idx = t + j * 512;
                    gload_lds16(src + idx, &Bbuf[(c + 1) & 1][idx]);
                }
            } else if (s + 1 < NSTAGE) {     // cross-stage prefetch into buf0
                const short8* src = frag + FRAG_S8;
                #pragma unroll
                for (int j = 0; j < 4; ++j) {
                    int idx = t + j * 512;
                    gload_lds16(src + idx, &Bbuf[0][idx]);
                }
            }
            // chunk c resident after this barrier (4 newest = c+1's loads)
            if (s == NSTAGE - 1 && c == 31) { BAR_VM0(); } else { BAR_VM4(); }

            const short8* B = Bbuf[c & 1];
            // prefetch ng0 kk0/kk1 frags (indices (ng*8 + kk*2 + h))
            short8 pbh0 = B[0 * 64 + lane];
            short8 pbl0 = B[1 * 64 + lane];
            short8 pbh1 = B[2 * 64 + lane];
            short8 pbl1 = B[3 * 64 + lane];
            #pragma unroll
            for (int ng = 0; ng < 4; ++ng) {
                // ---- fold pending (deferred one ng; other parity set)
                {
                    float cnv = sCn[cwp];
                    if ((ng & 1) == 0) {
                        #pragma unroll
                        for (int r = 0; r < 4; ++r) {
                            float dt = fmaf(-2.f, Ya[r], cnv);
                            upd2(d1[r], i1[r], d2[r], i2[r], dt, cwp);
                        }
                    } else {
                        #pragma unroll
                        for (int r = 0; r < 4; ++r) {
                            float dt = fmaf(-2.f, Xa[r], cnv);
                            upd2(d1[r], i1[r], d2[r], i2[r], dt, cwp);
                        }
                    }
                }
                // ---- chain ng: round-6 bitwise order (kk0,1 prefetched;
                //      kk2,3 + next-ng kk0,1 reads issued mid-chain)
                f32x4 ca = {0.f, 0.f, 0.f, 0.f};
                ca = MFMA16(Ahi[0], pbh0, ca);
                ca = MFMA16(Alo[0], pbh0, ca);
                ca = MFMA16(Ahi[0], pbl0, ca);
                ca = MFMA16(Ahi[1], pbh1, ca);
                ca = MFMA16(Alo[1], pbh1, ca);
                ca = MFMA16(Ahi[1], pbl1, ca);
                short8 bh2 = B[(ng * 8 + 4) * 64 + lane];
                short8 bl2 = B[(ng * 8 + 5) * 64 + lane];
                short8 bh3 = B[(ng * 8 + 6) * 64 + lane];
                short8 bl3 = B[(ng * 8 + 7) * 64 + lane];
                if (ng < 3) {
                    pbh0 = B[((ng + 1) * 8 + 0) * 64 + lane];
                    pbl0 = B[((ng + 1) * 8 + 1) * 64 + lane];
                    pbh1 = B[((ng + 1) * 8 + 2) * 64 + lane];
                    pbl1 = B[((ng + 1) * 8 + 3) * 64 + lane];
                }
                ca = MFMA16(Ahi[2], bh2, ca);
                ca = MFMA16(Alo[2], bh2, ca);
                ca = MFMA16(Ahi[2], bl2, ca);
                ca = MFMA16(Ahi[3], bh3, ca);
                ca = MFMA16(Alo[3], bh3, ca);
                ca = MFMA16(Ahi[3], bl3, ca);
                // ---- stash as pending
                if ((ng & 1) == 0) { Xa = ca; }
                else               { Ya = ca; }
                cwp = c * 64 + ng * 16 + m;
            }
            // release buf[c&1] for the DMA issued at iter c+1
            BAR_ONLY();
        }
        // final pending fold (set Y, from c=31 ng=3)
        {
            float cnv = sCn[cwp];
            #pragma unroll
            for (int r = 0; r < 4; ++r) {
                float dt = fmaf(-2.f, Ya[r], cnv);
                upd2(d1[r], i1[r], d2[r], i2[r], dt, cwp);
            }
        }

        // merge top-2 across the 16 codeword columns (m lanes)
        #pragma unroll
        for (int mm = 1; mm < 16; mm <<= 1) {
            #pragma unroll
            for (int r = 0; r < 4; ++r) {
                float od1 = __shfl_xor(d1[r], mm); int oi1 = __shfl_xor(i1[r], mm);
                float od2 = __shfl_xor(d2[r], mm); int oi2 = __shfl_xor(i2[r], mm);
                upd2(d1[r], i1[r], d2[r], i2[r], od1, oi1);
                upd2(d1[r], i1[r], d2[r], i2[r], od2, oi2);
            }
        }
        if (m == 0) {                        // redistribute: D rows -> A rows
            #pragma unroll
            for (int r = 0; r < 4; ++r)
                { sC1[w * 16 + q * 4 + r] = i1[r];
                  sC2[w * 16 + q * 4 + r] = i2[r]; }
        }
        BAR_LGKM();                          // sC visible; chunk-0 DMA flying

        {
            int ia = sC1[w * 16 + m];
            int ib = sC2[w * 16 + m];

            // exact fp32 recheck against R: lane covers k = kk*32 + q*8 .. +8
            float pa = 0.f, pb = 0.f, pr = 0.f;
            #pragma unroll
            for (int kk = 0; kk < 4; ++kk) {
                const float* pav = cbs + (size_t)ia * DDIM + kk * 32 + q * 8;
                const float* pbv = cbs + (size_t)ib * DDIM + kk * 32 + q * 8;
                float4 a0 = *(const float4*)pav, a1 = *(const float4*)(pav + 4);
                float4 b0 = *(const float4*)pbv, b1 = *(const float4*)(pbv + 4);
                float av[8] = {a0.x, a0.y, a0.z, a0.w, a1.x, a1.y, a1.z, a1.w};
                float bv[8] = {b0.x, b0.y, b0.z, b0.w, b1.x, b1.y, b1.z, b1.w};
                #pragma unroll
                for (int j = 0; j < 8; ++j) {
                    float rv = R[kk][j];
                    pa += rv * av[j];
                    pb += rv * bv[j];
                    pr += rv * rv;
                }
            }
            pa += __shfl_xor(pa, 16); pa += __shfl_xor(pa, 32);
            pb += __shfl_xor(pb, 16); pb += __shfl_xor(pb, 32);
            pr += __shfl_xor(pr, 16); pr += __shfl_xor(pr, 32);
            float dA = sCn[ia] - 2.f * pa;
            float dB = sCn[ib] - 2.f * pb;
            bool bw = (dB < dA) || (dB == dA && ib < ia);   // first-occurrence
            int  wi = bw ? ib : ia;
            if (q == 0) {
                out[IDX_OFF + pt * NSTAGE + s] = (float)wi;
                lossAcc += (bw ? dB : dA) + pr;             // ||c - r||^2
            }

            // exact update: R -= c_win; re-split frags; last stage: x_q = x - R
            const float* cwr = cbs + (size_t)wi * DDIM;
            #pragma unroll
            for (int kk = 0; kk < 4; ++kk) {
                const float* pwv = cwr + kk * 32 + q * 8;
                float4 w0 = *(const float4*)pwv, w1 = *(const float4*)(pwv + 4);
                float wv[8] = {w0.x, w0.y, w0.z, w0.w, w1.x, w1.y, w1.z, w1.w};
                short8 hi8, lo8;
                #pragma unroll
                for (int j = 0; j < 8; ++j) {
                    float v = R[kk][j] - wv[j];
                    R[kk][j] = v;
                    short hi = f2bf(v);
                    hi8[j] = hi;
                    lo8[j] = f2bf(v - bf2f(hi));
                }
                Ahi[kk] = hi8; Alo[kk] = lo8;
                if (s == NSTAGE - 1) {
                    const float* xp = x + pt * DDIM + kk * 32 + q * 8;
                    float4 x0 = *(const float4*)xp, x1 = *(const float4*)(xp + 4);
                    float* op = out + pt * DDIM + kk * 32 + q * 8;
                    *(float4*)op = make_float4(x0.x - R[kk][0], x0.y - R[kk][1],
                                               x0.z - R[kk][2], x0.w - R[kk][3]);
                    *(float4*)(op + 4) = make_float4(x1.x - R[kk][4], x1.y - R[kk][5],
                                                     x1.z - R[kk][6], x1.w - R[kk][7]);
                }
            }
        }

        // stage-end: sCn/sC reads done before next-stage sCn overwrite and
        // Bbuf reuse; keeps chunk-0 DMA in flight (no vmcnt drain)
        BAR_LGKM();
        if (s + 1 < NSTAGE) {                // stage s+1 cn -> LDS
            const float* cnn = ws + WS_CN + (s + 1) * KCB;
            gload_lds16(cnn + 4 * t, &sCn[4 * t]);
        }
    }

    // loss: wave reduce, one atomic per wave
    #pragma unroll
    for (int mm = 1; mm < 64; mm <<= 1)
        lossAcc += __shfl_xor(lossAcc, mm);
    if (lane == 0)
        atomicAdd(ws + WS_LOSS, lossAcc);
}

__global__ void rvq_finalize(const float* __restrict__ ws, float* __restrict__ out) {
    float sum = ws[0] + ws[1] + ws[2] + ws[3];
    out[XQ_SIZE] = (1.f + BETA_F) * sum /
                   ((float)NSTAGE * (float)N_PTS * (float)DDIM);
}

extern "C" void kernel_launch(void* const* d_in, const int* in_sizes, int n_in,
                              void* d_out, int out_size, void* d_ws, size_t ws_size,
                              hipStream_t stream) {
    const float* x  = (const float*)d_in[0];
    const float* cb = (const float*)d_in[1];
    float* out = (float*)d_out;
    float* ws  = (float*)d_ws;

    cnorm_init<<<512, 256, 0, stream>>>(cb, ws);
    frag_pack<<<1024, 256, 0, stream>>>(cb, ws);
    rvq_fused<<<512, 512, 0, stream>>>(x, cb, ws, out);
    rvq_finalize<<<1, 1, 0, stream>>>(ws, out);
}